// Round 1
// baseline (2521.280 us; speedup 1.0000x reference)
//
#include <hip/hip_runtime.h>
#include <math.h>

#define NB 128            // graphs
#define NN 1024           // nodes per graph
#define BNODES (NB*NN)    // 131072
#define NE 2097152        // edges
#define FH 64             // hidden
#define KK1 820
#define KK2 656
#define KK3 525

__global__ void k_fillf(float* p, float v, int n) {
  int i = blockIdx.x*256 + threadIdx.x;
  if (i < n) p[i] = v;
}
__global__ void k_filli(int* p, int v, int n) {
  int i = blockIdx.x*256 + threadIdx.x;
  if (i < n) p[i] = v;
}

// deg scatter into pre-filled (1.0f) buffer. mode 0: w=ea; 1: w=ea*mask; 2: w=mask
__global__ void k_deg(const int* __restrict__ ei, const float* __restrict__ ea,
                      const int* __restrict__ alive, float* __restrict__ deg, int mode) {
  int e = blockIdx.x*256 + threadIdx.x;
  if (e >= NE) return;
  int s = ei[e], d = ei[NE + e];
  float w;
  if (mode == 0) w = ea[e];
  else {
    if (!(alive[s] && alive[d])) return;
    w = (mode == 1) ? ea[e] : 1.0f;
  }
  if (w != 0.0f) atomicAdd(&deg[d], w);
}

__global__ void k_dinv(float* d) {
  int i = blockIdx.x*256 + threadIdx.x;
  if (i < BNODES) d[i] = 1.0f / sqrtf(d[i]);
}

// h = x @ W1, x is [BN,2], W1 is [2,64]
__global__ void k_lin1(const float* __restrict__ x, const float* __restrict__ W,
                       float* __restrict__ h) {
  int i = blockIdx.x*256 + threadIdx.x;
  if (i >= BNODES*FH) return;
  int node = i >> 6, f = i & 63;
  h[i] = x[2*node]*W[f] + x[2*node+1]*W[FH + f];
}

// out = xin @ W (64x64), W staged in LDS, 4 nodes per 256-thread block, grid-stride
__global__ void k_lin64(const float* __restrict__ xin, const float* __restrict__ W,
                        float* __restrict__ out) {
  __shared__ float sW[FH*FH];
  int t = threadIdx.x;
  for (int i = t; i < FH*FH; i += 256) sW[i] = W[i];
  __syncthreads();
  int r = t >> 6, f = t & 63;
  for (int g0 = blockIdx.x; g0 < BNODES/4; g0 += gridDim.x) {
    int node = g0*4 + r;
    const float* xr = xin + (size_t)node*FH;
    float acc = 0.f;
    #pragma unroll
    for (int k = 0; k < FH; ++k) acc = fmaf(xr[k], sW[k*FH + f], acc);
    out[(size_t)node*FH + f] = acc;
  }
}

// out = dinv^2 * h + b   (GCN self-loop term + bias, scatter accumulates on top)
__global__ void k_selfinit(const float* __restrict__ h, const float* __restrict__ dinv,
                           const float* __restrict__ b, float* __restrict__ out) {
  int i = blockIdx.x*256 + threadIdx.x;
  if (i >= BNODES*FH) return;
  int node = i >> 6, f = i & 63;
  float di = dinv[node];
  out[i] = di*di*h[i] + b[f];
}

// per (edge, feature): out[dst,f] += dinv[s]*w*dinv[d] * h[src,f]
__global__ void k_scat64(const int* __restrict__ ei, const float* __restrict__ ea,
                         const int* __restrict__ alive, const float* __restrict__ dinv,
                         const float* __restrict__ h, float* __restrict__ out, int mode) {
  int idx = blockIdx.x*256 + threadIdx.x;   // NE*64 = 134217728 < 2^31
  int e = idx >> 6, f = idx & 63;
  if (e >= NE) return;
  int s = ei[e], d = ei[NE + e];
  float w;
  if (mode == 0) w = ea[e];
  else {
    if (!(alive[s] && alive[d])) return;
    w = (mode == 1) ? ea[e] : 1.0f;
  }
  if (w == 0.0f) return;
  float norm = dinv[s]*w*dinv[d];
  atomicAdd(&out[(size_t)d*FH + f], norm * h[(size_t)s*FH + f]);
}

__global__ void k_relu(float* p, int n) {
  int i = blockIdx.x*256 + threadIdx.x;
  if (i < n) p[i] = fmaxf(p[i], 0.f);
}

// sse[i] = dot(h[i,:], Wp) — one 64-lane wave per node, shuffle reduce
__global__ void k_sself(const float* __restrict__ h, const float* __restrict__ Wp,
                        float* __restrict__ sse) {
  int gid = blockIdx.x*256 + threadIdx.x;
  if (gid >= BNODES*FH) return;
  int node = gid >> 6, lane = threadIdx.x & 63;
  float v = h[gid] * Wp[lane];
  #pragma unroll
  for (int off = 32; off > 0; off >>= 1) v += __shfl_xor(v, off);
  if (lane == 0) sse[node] = v;
}

__global__ void k_sinit(const float* __restrict__ sse, const float* __restrict__ dinv,
                        const float* __restrict__ bp, float* __restrict__ score) {
  int i = blockIdx.x*256 + threadIdx.x;
  if (i >= BNODES) return;
  float di = dinv[i];
  score[i] = di*di*sse[i] + bp[0];
}

__global__ void k_sscat(const int* __restrict__ ei, const int* __restrict__ alive,
                        const float* __restrict__ dinv, const float* __restrict__ sse,
                        float* __restrict__ score) {
  int e = blockIdx.x*256 + threadIdx.x;
  if (e >= NE) return;
  int s = ei[e], d = ei[NE + e];
  if (!(alive[s] && alive[d])) return;
  atomicAdd(&score[d], dinv[s]*dinv[d]*sse[s]);
}

// per-graph top-k (ties -> lower index, matches jax.lax.top_k) + x *= tanh(score) / zero
__global__ void k_topk(const float* __restrict__ score, const int* __restrict__ alive,
                       int k, float* __restrict__ h, int* __restrict__ aliveNext) {
  __shared__ float s[NN];
  __shared__ float tm[NN];
  int b = blockIdx.x, t = threadIdx.x;
  int node = b*NN + t;
  float raw = score[node];
  float masked = alive[node] ? raw : -INFINITY;
  s[t] = masked;
  __syncthreads();
  int rank = 0;
  for (int j = 0; j < NN; ++j) {
    float o = s[j];
    rank += (o > masked) || (o == masked && j < t);
  }
  int sel = (rank < k) ? 1 : 0;
  aliveNext[node] = sel;
  tm[t] = sel ? tanhf(raw) : 0.0f;
  __syncthreads();
  float* hb = h + (size_t)b*NN*FH;
  for (int i = t; i < NN*FH; i += NN) hb[i] *= tm[i >> 6];
}

// g[b, 0:64] += max over alive; g[b, 64:128] += mean over alive (count = k)
__global__ void k_readout(const float* __restrict__ h, const int* __restrict__ alive,
                          float kf, float* __restrict__ g) {
  __shared__ float smx[4][FH];
  __shared__ float ssm[4][FH];
  int b = blockIdx.x, t = threadIdx.x;
  int r = t >> 6, f = t & 63;
  float mx = -INFINITY, sm = 0.f;
  for (int n = r; n < NN; n += 4) {
    int node = b*NN + n;
    if (alive[node]) {
      float v = h[(size_t)node*FH + f];
      mx = fmaxf(mx, v);
      sm += v;
    }
  }
  smx[r][f] = mx; ssm[r][f] = sm;
  __syncthreads();
  if (r == 0) {
    mx = fmaxf(fmaxf(smx[0][f], smx[1][f]), fmaxf(smx[2][f], smx[3][f]));
    sm = ssm[0][f] + ssm[1][f] + ssm[2][f] + ssm[3][f];
    g[b*2*FH + f] += mx;
    g[b*2*FH + FH + f] += sm / kf;
  }
}

// MLP head + log_softmax, one 64-thread block per graph
__global__ void k_mlp(const float* __restrict__ g,
                      const float* __restrict__ Wl1, const float* __restrict__ bl1,
                      const float* __restrict__ Wl2, const float* __restrict__ bl2,
                      const float* __restrict__ Wl3, const float* __restrict__ bl3,
                      float* __restrict__ out) {
  __shared__ float sg[2*FH];
  __shared__ float l1[FH];
  __shared__ float l2[FH/2];
  __shared__ float l3[2];
  int b = blockIdx.x, t = threadIdx.x;
  sg[t] = g[b*2*FH + t];
  sg[FH + t] = g[b*2*FH + FH + t];
  __syncthreads();
  float acc = bl1[t];
  #pragma unroll
  for (int k = 0; k < 2*FH; ++k) acc = fmaf(sg[k], Wl1[k*FH + t], acc);
  l1[t] = fmaxf(acc, 0.f);
  __syncthreads();
  if (t < 32) {
    float a2 = bl2[t];
    #pragma unroll
    for (int k = 0; k < FH; ++k) a2 = fmaf(l1[k], Wl2[k*32 + t], a2);
    l2[t] = fmaxf(a2, 0.f);
  }
  __syncthreads();
  if (t < 2) {
    float a3 = bl3[t];
    #pragma unroll
    for (int k = 0; k < 32; ++k) a3 = fmaf(l2[k], Wl3[k*2 + t], a3);
    l3[t] = a3;
  }
  __syncthreads();
  if (t == 0) {
    float m = fmaxf(l3[0], l3[1]);
    float lse = m + logf(expf(l3[0]-m) + expf(l3[1]-m));
    out[b*2+0] = l3[0] - lse;
    out[b*2+1] = l3[1] - lse;
  }
}

extern "C" void kernel_launch(void* const* d_in, const int* in_sizes, int n_in,
                              void* d_out, int out_size, void* d_ws, size_t ws_size,
                              hipStream_t stream) {
  const float* x   = (const float*)d_in[0];
  const float* ea  = (const float*)d_in[1];
  const float* W1  = (const float*)d_in[2];
  const float* b1  = (const float*)d_in[3];
  const float* Wp1 = (const float*)d_in[4];
  const float* bp1 = (const float*)d_in[5];
  const float* W2  = (const float*)d_in[6];
  const float* b2  = (const float*)d_in[7];
  const float* Wp2 = (const float*)d_in[8];
  const float* bp2 = (const float*)d_in[9];
  const float* W3  = (const float*)d_in[10];
  const float* b3  = (const float*)d_in[11];
  const float* Wp3 = (const float*)d_in[12];
  const float* bp3 = (const float*)d_in[13];
  const float* Wl1 = (const float*)d_in[14];
  const float* bl1 = (const float*)d_in[15];
  const float* Wl2 = (const float*)d_in[16];
  const float* bl2 = (const float*)d_in[17];
  const float* Wl3 = (const float*)d_in[18];
  const float* bl3 = (const float*)d_in[19];
  const int*   ei  = (const int*)d_in[20];
  float* out = (float*)d_out;

  float* hA    = (float*)d_ws;
  float* hB    = hA + (size_t)BNODES*FH;
  float* dinv  = hB + (size_t)BNODES*FH;
  float* sse   = dinv + BNODES;
  float* score = sse + BNODES;
  int* aliveA  = (int*)(score + BNODES);
  int* aliveB  = aliveA + BNODES;
  float* g     = (float*)(aliveB + BNODES);

  const int TB = 256;
  const int gE = (NE + TB - 1) / TB;
  const int gNH = (BNODES*FH) / TB;
  const int gN = (BNODES + TB - 1) / TB;
  const int gScat = (NE*FH) / TB;

  k_fillf<<<(NB*2*FH + TB-1)/TB, TB, 0, stream>>>(g, 0.f, NB*2*FH);
  k_filli<<<gN, TB, 0, stream>>>(aliveA, 1, BNODES);

  // ===== GCN1 (w = edge_attr) =====
  k_fillf<<<gN, TB, 0, stream>>>(dinv, 1.0f, BNODES);
  k_deg<<<gE, TB, 0, stream>>>(ei, ea, aliveA, dinv, 0);
  k_dinv<<<gN, TB, 0, stream>>>(dinv);
  k_lin1<<<gNH, TB, 0, stream>>>(x, W1, hB);
  k_selfinit<<<gNH, TB, 0, stream>>>(hB, dinv, b1, hA);
  k_scat64<<<gScat, TB, 0, stream>>>(ei, ea, aliveA, dinv, hB, hA, 0);
  k_relu<<<gNH, TB, 0, stream>>>(hA, BNODES*FH);
  // ===== SAGPool1 =====
  k_sself<<<gNH, TB, 0, stream>>>(hA, Wp1, sse);
  k_fillf<<<gN, TB, 0, stream>>>(dinv, 1.0f, BNODES);
  k_deg<<<gE, TB, 0, stream>>>(ei, ea, aliveA, dinv, 2);
  k_dinv<<<gN, TB, 0, stream>>>(dinv);
  k_sinit<<<gN, TB, 0, stream>>>(sse, dinv, bp1, score);
  k_sscat<<<gE, TB, 0, stream>>>(ei, aliveA, dinv, sse, score);
  k_topk<<<NB, NN, 0, stream>>>(score, aliveA, KK1, hA, aliveB);
  k_readout<<<NB, 256, 0, stream>>>(hA, aliveB, (float)KK1, g);

  // ===== GCN2 (w = edge_attr * mask(aliveB)) =====
  k_fillf<<<gN, TB, 0, stream>>>(dinv, 1.0f, BNODES);
  k_deg<<<gE, TB, 0, stream>>>(ei, ea, aliveB, dinv, 1);
  k_dinv<<<gN, TB, 0, stream>>>(dinv);
  k_lin64<<<4096, TB, 0, stream>>>(hA, W2, hB);
  k_selfinit<<<gNH, TB, 0, stream>>>(hB, dinv, b2, hA);
  k_scat64<<<gScat, TB, 0, stream>>>(ei, ea, aliveB, dinv, hB, hA, 1);
  k_relu<<<gNH, TB, 0, stream>>>(hA, BNODES*FH);
  // ===== SAGPool2 =====
  k_sself<<<gNH, TB, 0, stream>>>(hA, Wp2, sse);
  k_fillf<<<gN, TB, 0, stream>>>(dinv, 1.0f, BNODES);
  k_deg<<<gE, TB, 0, stream>>>(ei, ea, aliveB, dinv, 2);
  k_dinv<<<gN, TB, 0, stream>>>(dinv);
  k_sinit<<<gN, TB, 0, stream>>>(sse, dinv, bp2, score);
  k_sscat<<<gE, TB, 0, stream>>>(ei, aliveB, dinv, sse, score);
  k_topk<<<NB, NN, 0, stream>>>(score, aliveB, KK2, hA, aliveA);
  k_readout<<<NB, 256, 0, stream>>>(hA, aliveA, (float)KK2, g);

  // ===== GCN3 (w = mask(aliveA), conv3 has no edge_weight) =====
  k_fillf<<<gN, TB, 0, stream>>>(dinv, 1.0f, BNODES);
  k_deg<<<gE, TB, 0, stream>>>(ei, ea, aliveA, dinv, 2);
  k_dinv<<<gN, TB, 0, stream>>>(dinv);
  k_lin64<<<4096, TB, 0, stream>>>(hA, W3, hB);
  k_selfinit<<<gNH, TB, 0, stream>>>(hB, dinv, b3, hA);
  k_scat64<<<gScat, TB, 0, stream>>>(ei, ea, aliveA, dinv, hB, hA, 2);
  k_relu<<<gNH, TB, 0, stream>>>(hA, BNODES*FH);
  // ===== SAGPool3 =====
  k_sself<<<gNH, TB, 0, stream>>>(hA, Wp3, sse);
  k_fillf<<<gN, TB, 0, stream>>>(dinv, 1.0f, BNODES);
  k_deg<<<gE, TB, 0, stream>>>(ei, ea, aliveA, dinv, 2);
  k_dinv<<<gN, TB, 0, stream>>>(dinv);
  k_sinit<<<gN, TB, 0, stream>>>(sse, dinv, bp3, score);
  k_sscat<<<gE, TB, 0, stream>>>(ei, aliveA, dinv, sse, score);
  k_topk<<<NB, NN, 0, stream>>>(score, aliveA, KK3, hA, aliveB);
  k_readout<<<NB, 256, 0, stream>>>(hA, aliveB, (float)KK3, g);

  k_mlp<<<NB, FH, 0, stream>>>(g, Wl1, bl1, Wl2, bl2, Wl3, bl3, out);
}

// Round 2
// 1479.096 us; speedup vs baseline: 1.7046x; 1.7046x over previous
//
#include <hip/hip_runtime.h>
#include <math.h>

#define NB 128            // graphs
#define NN 1024           // nodes per graph
#define BNODES (NB*NN)    // 131072
#define NE 2097152        // edges
#define FH 64             // hidden
#define KK1 820
#define KK2 656
#define KK3 525

// ---------- CSR build ----------
__global__ void k_init(int* __restrict__ cnt, int* __restrict__ aliveA, float* __restrict__ g) {
  int i = blockIdx.x*256 + threadIdx.x;
  if (i < BNODES) { cnt[i] = 0; aliveA[i] = 1; }
  if (i < NB*2*FH) g[i] = 0.f;
}

__global__ void k_count(const int* __restrict__ ei, int* __restrict__ cnt) {
  int e = blockIdx.x*256 + threadIdx.x;
  if (e < NE) atomicAdd(&cnt[ei[NE + e]], 1);
}

// single-block exclusive scan over 131072 counts -> rowptr, cursor
__global__ void k_scan(const int* __restrict__ cnt, int* __restrict__ rowptr,
                       int* __restrict__ cursor) {
  __shared__ int ps[1024];
  int t = threadIdx.x;
  int base = t * 128;
  int s = 0;
  for (int j = 0; j < 128; ++j) s += cnt[base + j];
  ps[t] = s;
  __syncthreads();
  for (int off = 1; off < 1024; off <<= 1) {
    int v = (t >= off) ? ps[t - off] : 0;
    __syncthreads();
    ps[t] += v;
    __syncthreads();
  }
  int run = (t == 0) ? 0 : ps[t - 1];
  for (int j = 0; j < 128; ++j) {
    int c = cnt[base + j];
    rowptr[base + j] = run;
    cursor[base + j] = run;
    run += c;
  }
  if (t == 1023) rowptr[BNODES] = run;
}

__global__ void k_fill(const int* __restrict__ ei, int* __restrict__ cursor,
                       int* __restrict__ csr_eid) {
  int e = blockIdx.x*256 + threadIdx.x;
  if (e >= NE) return;
  int d = ei[NE + e];
  int pos = atomicAdd(&cursor[d], 1);
  csr_eid[pos] = e;
}

// ---------- degrees (weighted for GCN, unweighted for scoring) in one pass ----------
// MODE 0: w=ea, mask=all  | MODE 1: w=ea*mask | MODE 2: w=mask
template<int MODE>
__global__ void k_degs(const int* __restrict__ rowptr, const int* __restrict__ csr_eid,
                       const int* __restrict__ ei, const float* __restrict__ ea,
                       const int* __restrict__ alive,
                       float* __restrict__ dinvW, float* __restrict__ dinvU) {
  int d = blockIdx.x*256 + threadIdx.x;
  if (d >= BNODES) return;
  float sW = 0.f, sU = 0.f;
  bool dA = (MODE == 0) || (alive[d] != 0);
  if (dA) {
    int r1 = rowptr[d+1];
    for (int j = rowptr[d]; j < r1; ++j) {
      int eid = csr_eid[j];
      if (MODE != 0 && !alive[ei[eid]]) continue;
      float w = (MODE == 2) ? 1.f : ea[eid];
      sW += w;
      sU += 1.f;
    }
  }
  dinvW[d] = rsqrtf(1.f + sW);
  dinvU[d] = rsqrtf(1.f + sU);
}

// ---------- feature transforms ----------
__global__ void k_lin1(const float* __restrict__ x, const float* __restrict__ W,
                       float* __restrict__ h) {
  int i = blockIdx.x*256 + threadIdx.x;
  if (i >= BNODES*FH) return;
  int node = i >> 6, f = i & 63;
  h[i] = x[2*node]*W[f] + x[2*node+1]*W[FH + f];
}

__global__ void k_lin64(const float* __restrict__ xin, const float* __restrict__ W,
                        float* __restrict__ out) {
  __shared__ float sW[FH*FH];
  int t = threadIdx.x;
  for (int i = t; i < FH*FH; i += 256) sW[i] = W[i];
  __syncthreads();
  int r = t >> 6, f = t & 63;
  for (int g0 = blockIdx.x; g0 < BNODES/4; g0 += gridDim.x) {
    int node = g0*4 + r;
    const float* xr = xin + (size_t)node*FH;
    float acc = 0.f;
    #pragma unroll
    for (int k = 0; k < FH; ++k) acc = fmaf(xr[k], sW[k*FH + f], acc);
    out[(size_t)node*FH + f] = acc;
  }
}

// ---------- fused GCN gather: self term + bias + edge gather + relu + scoring dot ----------
template<int MODE>
__global__ void k_gather(const int* __restrict__ rowptr, const int* __restrict__ csr_eid,
                         const int* __restrict__ ei, const float* __restrict__ ea,
                         const int* __restrict__ alive, const float* __restrict__ dinv,
                         const float* __restrict__ hB, const float* __restrict__ b,
                         const float* __restrict__ Wp,
                         float* __restrict__ hA, float* __restrict__ sse) {
  int d = (blockIdx.x*256 + threadIdx.x) >> 6;   // one wave per dst node
  int lane = threadIdx.x & 63;
  if (d >= BNODES) return;
  float dd = dinv[d];
  float acc = dd*dd*hB[(size_t)d*FH + lane] + b[lane];
  bool dA = (MODE == 0) || (alive[d] != 0);
  if (dA) {
    int r1 = rowptr[d+1];
    for (int j = rowptr[d]; j < r1; ++j) {
      int eid = csr_eid[j];
      int s = ei[eid];
      if (MODE != 0 && !alive[s]) continue;
      float w = (MODE == 2) ? 1.f : ea[eid];
      acc += dd * dinv[s] * w * hB[(size_t)s*FH + lane];
    }
  }
  acc = fmaxf(acc, 0.f);
  hA[(size_t)d*FH + lane] = acc;
  float v = acc * Wp[lane];
  #pragma unroll
  for (int off = 32; off; off >>= 1) v += __shfl_xor(v, off);
  if (lane == 0) sse[d] = v;
}

// ---------- scoring GCN (F=1), unweighted masked adjacency ----------
__global__ void k_score(const int* __restrict__ rowptr, const int* __restrict__ csr_eid,
                        const int* __restrict__ ei, const int* __restrict__ alive,
                        const float* __restrict__ dinvU, const float* __restrict__ sse,
                        const float* __restrict__ bp, float* __restrict__ score) {
  int d = blockIdx.x*256 + threadIdx.x;
  if (d >= BNODES) return;
  float du = dinvU[d];
  float acc = du*du*sse[d] + bp[0];
  if (alive[d]) {
    int r1 = rowptr[d+1];
    for (int j = rowptr[d]; j < r1; ++j) {
      int eid = csr_eid[j];
      int s = ei[eid];
      if (alive[s]) acc += du * dinvU[s] * sse[s];
    }
  }
  score[d] = acc;
}

// ---------- top-k (exact jax.lax.top_k tie semantics) + pool-scale + readout ----------
__global__ void k_topk_readout(const float* __restrict__ score, const int* __restrict__ alive,
                               int k, float kf, float* __restrict__ h,
                               int* __restrict__ aliveNext, float* __restrict__ g) {
  __shared__ float s[NN];
  __shared__ float tm[NN];
  __shared__ float smx[16][FH];
  __shared__ float ssm[16][FH];
  int b = blockIdx.x, t = threadIdx.x;
  int node = b*NN + t;
  float raw = score[node];
  float masked = alive[node] ? raw : -INFINITY;
  s[t] = masked;
  __syncthreads();
  int rank = 0;
  for (int j = 0; j < NN; ++j) {
    float o = s[j];
    rank += (o > masked) || (o == masked && j < t);
  }
  int sel = (rank < k) ? 1 : 0;
  aliveNext[node] = sel;
  __syncthreads();
  tm[t] = sel ? tanhf(raw) : 0.f;
  s[t] = sel ? 1.f : 0.f;
  __syncthreads();
  int f = t & 63, r = t >> 6;          // wave r handles nodes r, r+16, ...
  float mx = -INFINITY, sm = 0.f;
  float* hb = h + (size_t)b*NN*FH;
  for (int kk = 0; kk < 64; ++kk) {
    int n = r + kk*16;
    float tv = tm[n];
    size_t idx = (size_t)n*FH + f;
    float v = hb[idx] * tv;
    hb[idx] = v;
    if (s[n] != 0.f) { mx = fmaxf(mx, v); sm += v; }
  }
  smx[r][f] = mx; ssm[r][f] = sm;
  __syncthreads();
  if (t < FH) {
    float m2 = -INFINITY, s2 = 0.f;
    #pragma unroll
    for (int rr = 0; rr < 16; ++rr) { m2 = fmaxf(m2, smx[rr][t]); s2 += ssm[rr][t]; }
    g[b*2*FH + t] += m2;
    g[b*2*FH + FH + t] += s2 / kf;
  }
}

// ---------- MLP head + log_softmax ----------
__global__ void k_mlp(const float* __restrict__ g,
                      const float* __restrict__ Wl1, const float* __restrict__ bl1,
                      const float* __restrict__ Wl2, const float* __restrict__ bl2,
                      const float* __restrict__ Wl3, const float* __restrict__ bl3,
                      float* __restrict__ out) {
  __shared__ float sg[2*FH];
  __shared__ float l1[FH];
  __shared__ float l2[FH/2];
  __shared__ float l3[2];
  int b = blockIdx.x, t = threadIdx.x;
  sg[t] = g[b*2*FH + t];
  sg[FH + t] = g[b*2*FH + FH + t];
  __syncthreads();
  float acc = bl1[t];
  #pragma unroll
  for (int k = 0; k < 2*FH; ++k) acc = fmaf(sg[k], Wl1[k*FH + t], acc);
  l1[t] = fmaxf(acc, 0.f);
  __syncthreads();
  if (t < 32) {
    float a2 = bl2[t];
    #pragma unroll
    for (int k = 0; k < FH; ++k) a2 = fmaf(l1[k], Wl2[k*32 + t], a2);
    l2[t] = fmaxf(a2, 0.f);
  }
  __syncthreads();
  if (t < 2) {
    float a3 = bl3[t];
    #pragma unroll
    for (int k = 0; k < 32; ++k) a3 = fmaf(l2[k], Wl3[k*2 + t], a3);
    l3[t] = a3;
  }
  __syncthreads();
  if (t == 0) {
    float m = fmaxf(l3[0], l3[1]);
    float lse = m + logf(expf(l3[0]-m) + expf(l3[1]-m));
    out[b*2+0] = l3[0] - lse;
    out[b*2+1] = l3[1] - lse;
  }
}

extern "C" void kernel_launch(void* const* d_in, const int* in_sizes, int n_in,
                              void* d_out, int out_size, void* d_ws, size_t ws_size,
                              hipStream_t stream) {
  const float* x   = (const float*)d_in[0];
  const float* ea  = (const float*)d_in[1];
  const float* W1  = (const float*)d_in[2];
  const float* b1  = (const float*)d_in[3];
  const float* Wp1 = (const float*)d_in[4];
  const float* bp1 = (const float*)d_in[5];
  const float* W2  = (const float*)d_in[6];
  const float* b2  = (const float*)d_in[7];
  const float* Wp2 = (const float*)d_in[8];
  const float* bp2 = (const float*)d_in[9];
  const float* W3  = (const float*)d_in[10];
  const float* b3  = (const float*)d_in[11];
  const float* Wp3 = (const float*)d_in[12];
  const float* bp3 = (const float*)d_in[13];
  const float* Wl1 = (const float*)d_in[14];
  const float* bl1 = (const float*)d_in[15];
  const float* Wl2 = (const float*)d_in[16];
  const float* bl2 = (const float*)d_in[17];
  const float* Wl3 = (const float*)d_in[18];
  const float* bl3 = (const float*)d_in[19];
  const int*   ei  = (const int*)d_in[20];
  float* out = (float*)d_out;

  float* hA    = (float*)d_ws;                       // BNODES*FH
  float* hB    = hA + (size_t)BNODES*FH;             // BNODES*FH
  float* dinvW = hB + (size_t)BNODES*FH;             // BNODES
  float* dinvU = dinvW + BNODES;                     // BNODES
  float* sse   = dinvU + BNODES;                     // BNODES
  float* score = sse + BNODES;                       // BNODES
  float* g     = score + BNODES;                     // NB*2*FH
  int* aliveA  = (int*)(g + NB*2*FH);                // BNODES
  int* aliveB  = aliveA + BNODES;                    // BNODES
  int* cnt     = aliveB + BNODES;                    // BNODES
  int* rowptr  = cnt + BNODES;                       // BNODES+1
  int* cursor  = rowptr + BNODES + 1;                // BNODES
  int* csr_eid = cursor + BNODES;                    // NE

  const int TB = 256;
  const int gE  = NE / TB;
  const int gN  = BNODES / TB;
  const int gNH = BNODES*FH / TB;
  const int gW  = BNODES*64 / TB;   // one wave per node

  // CSR build (reused by all 6 aggregation passes)
  k_init<<<gN, TB, 0, stream>>>(cnt, aliveA, g);
  k_count<<<gE, TB, 0, stream>>>(ei, cnt);
  k_scan<<<1, 1024, 0, stream>>>(cnt, rowptr, cursor);
  k_fill<<<gE, TB, 0, stream>>>(ei, cursor, csr_eid);

  // ===== Layer 1 (w = edge_attr, all alive) =====
  k_degs<0><<<gN, TB, 0, stream>>>(rowptr, csr_eid, ei, ea, aliveA, dinvW, dinvU);
  k_lin1<<<gNH, TB, 0, stream>>>(x, W1, hB);
  k_gather<0><<<gW, TB, 0, stream>>>(rowptr, csr_eid, ei, ea, aliveA, dinvW, hB, b1, Wp1, hA, sse);
  k_score<<<gN, TB, 0, stream>>>(rowptr, csr_eid, ei, aliveA, dinvU, sse, bp1, score);
  k_topk_readout<<<NB, NN, 0, stream>>>(score, aliveA, KK1, (float)KK1, hA, aliveB, g);

  // ===== Layer 2 (w = edge_attr * mask(a1)) =====
  k_degs<1><<<gN, TB, 0, stream>>>(rowptr, csr_eid, ei, ea, aliveB, dinvW, dinvU);
  k_lin64<<<4096, TB, 0, stream>>>(hA, W2, hB);
  k_gather<1><<<gW, TB, 0, stream>>>(rowptr, csr_eid, ei, ea, aliveB, dinvW, hB, b2, Wp2, hA, sse);
  k_score<<<gN, TB, 0, stream>>>(rowptr, csr_eid, ei, aliveB, dinvU, sse, bp2, score);
  k_topk_readout<<<NB, NN, 0, stream>>>(score, aliveB, KK2, (float)KK2, hA, aliveA, g);

  // ===== Layer 3 (w = mask(a2), conv3 unweighted) =====
  k_degs<2><<<gN, TB, 0, stream>>>(rowptr, csr_eid, ei, ea, aliveA, dinvW, dinvU);
  k_lin64<<<4096, TB, 0, stream>>>(hA, W3, hB);
  k_gather<2><<<gW, TB, 0, stream>>>(rowptr, csr_eid, ei, ea, aliveA, dinvW, hB, b3, Wp3, hA, sse);
  k_score<<<gN, TB, 0, stream>>>(rowptr, csr_eid, ei, aliveA, dinvU, sse, bp3, score);
  k_topk_readout<<<NB, NN, 0, stream>>>(score, aliveA, KK3, (float)KK3, hA, aliveB, g);

  k_mlp<<<NB, FH, 0, stream>>>(g, Wl1, bl1, Wl2, bl2, Wl3, bl3, out);
}

// Round 4
// 911.304 us; speedup vs baseline: 2.7667x; 1.6231x over previous
//
#include <hip/hip_runtime.h>
#include <math.h>

#define NB 128            // graphs
#define NN 1024           // nodes per graph
#define BNODES (NB*NN)    // 131072
#define NE 2097152        // edges
#define FH 64             // hidden
#define KK1 820
#define KK2 656
#define KK3 525

// ---------- CSR build ----------
__global__ void k_init(int* __restrict__ cnt, int* __restrict__ aliveA, float* __restrict__ g) {
  int i = blockIdx.x*256 + threadIdx.x;
  if (i < BNODES) { cnt[i] = 0; aliveA[i] = 1; }
  if (i < NB*2*FH) g[i] = 0.f;
}

__global__ void k_count(const int* __restrict__ ei, int* __restrict__ cnt) {
  int e = blockIdx.x*256 + threadIdx.x;
  if (e < NE) atomicAdd(&cnt[ei[NE + e]], 1);
}

// single-block exclusive scan over 131072 counts -> rowptr, cursor
__global__ void k_scan(const int* __restrict__ cnt, int* __restrict__ rowptr,
                       int* __restrict__ cursor) {
  __shared__ int ps[1024];
  int t = threadIdx.x;
  int base = t * 128;
  int s = 0;
  for (int j = 0; j < 128; ++j) s += cnt[base + j];
  ps[t] = s;
  __syncthreads();
  for (int off = 1; off < 1024; off <<= 1) {
    int v = (t >= off) ? ps[t - off] : 0;
    __syncthreads();
    ps[t] += v;
    __syncthreads();
  }
  int run = (t == 0) ? 0 : ps[t - 1];
  for (int j = 0; j < 128; ++j) {
    int c = cnt[base + j];
    rowptr[base + j] = run;
    cursor[base + j] = run;
    run += c;
  }
  if (t == 1023) rowptr[BNODES] = run;
}

// inline edge payload into CSR order: kills eid double-indirection later
__global__ void k_fill(const int* __restrict__ ei, const float* __restrict__ ea,
                       int* __restrict__ cursor,
                       int* __restrict__ csr_src, float* __restrict__ csr_w) {
  int e = blockIdx.x*256 + threadIdx.x;
  if (e >= NE) return;
  int s = ei[e], d = ei[NE + e];
  int pos = atomicAdd(&cursor[d], 1);
  csr_src[pos] = s;
  csr_w[pos] = ea[e];
}

// ---------- degrees (weighted for GCN, unweighted for scoring) in one pass ----------
// MODE 0: w=ea, all alive | MODE 1: w=ea*mask | MODE 2: w=mask
template<int MODE>
__global__ void k_degs(const int* __restrict__ rowptr, const int* __restrict__ csr_src,
                       const float* __restrict__ csr_w, const int* __restrict__ alive,
                       float* __restrict__ dinvW, float* __restrict__ dinvU) {
  int d = blockIdx.x*256 + threadIdx.x;
  if (d >= BNODES) return;
  float sW = 0.f, sU = 0.f;
  if ((MODE == 0) || alive[d]) {
    int r1 = rowptr[d+1];
    for (int j = rowptr[d]; j < r1; ++j) {
      if (MODE != 0 && !alive[csr_src[j]]) continue;
      sW += (MODE == 2) ? 1.f : csr_w[j];
      sU += 1.f;
    }
  }
  dinvW[d] = rsqrtf(1.f + sW);
  dinvU[d] = rsqrtf(1.f + sU);
}

// ---------- feature transforms ----------
__global__ void k_lin1(const float* __restrict__ x, const float* __restrict__ W,
                       float* __restrict__ h) {
  int i = blockIdx.x*256 + threadIdx.x;
  if (i >= BNODES*FH) return;
  int node = i >> 6, f = i & 63;
  h[i] = x[2*node]*W[f] + x[2*node+1]*W[FH + f];
}

__global__ void k_lin64(const float* __restrict__ xin, const float* __restrict__ W,
                        float* __restrict__ out) {
  __shared__ float sW[FH*FH];
  int t = threadIdx.x;
  for (int i = t; i < FH*FH; i += 256) sW[i] = W[i];
  __syncthreads();
  int r = t >> 6, f = t & 63;
  for (int g0 = blockIdx.x; g0 < BNODES/4; g0 += gridDim.x) {
    int node = g0*4 + r;
    const float* xr = xin + (size_t)node*FH;
    float acc = 0.f;
    #pragma unroll
    for (int k = 0; k < FH; ++k) acc = fmaf(xr[k], sW[k*FH + f], acc);
    out[(size_t)node*FH + f] = acc;
  }
}

// ---------- fused GCN gather ----------
// one wave per dst node, lane = feature. Lane-parallel edge prefetch + shfl
// broadcast; XCD-swizzled grid so each graph's hB slice stays in one L2.
template<int MODE>
__global__ void k_gather(const int* __restrict__ rowptr, const int* __restrict__ csr_src,
                         const float* __restrict__ csr_w, const int* __restrict__ alive,
                         const float* __restrict__ dinv,
                         const float* __restrict__ hB, const float* __restrict__ b,
                         const float* __restrict__ Wp,
                         float* __restrict__ hA, float* __restrict__ sse) {
  int cpx = gridDim.x >> 3;                          // gridDim multiple of 8
  int orig = (blockIdx.x & 7) * cpx + (blockIdx.x >> 3);
  int lane = threadIdx.x & 63;
  int d = orig*4 + (threadIdx.x >> 6);
  float dd = dinv[d];
  float acc = dd*dd*hB[(size_t)d*FH + lane] + b[lane];
  bool dA = (MODE == 0) || (alive[d] != 0);
  if (dA) {
    int r0 = rowptr[d], r1 = rowptr[d+1];
    for (int base = r0; base < r1; base += 64) {
      int m = min(64, r1 - base);
      int sj = 0; float cj = 0.f;
      if (lane < m) {
        sj = csr_src[base + lane];
        float w = (MODE == 2) ? 1.f : csr_w[base + lane];
        bool ok = (MODE == 0) || (alive[sj] != 0);
        cj = ok ? dinv[sj] * w * dd : 0.f;
      }
      for (int j = 0; j < m; ++j) {
        int s   = __shfl(sj, j);
        float c = __shfl(cj, j);
        if (c != 0.f) acc += c * hB[(size_t)s*FH + lane];   // wave-uniform branch
      }
    }
  }
  acc = fmaxf(acc, 0.f);
  hA[(size_t)d*FH + lane] = acc;
  float v = acc * Wp[lane];
  #pragma unroll
  for (int off = 32; off; off >>= 1) v += __shfl_xor(v, off);
  if (lane == 0) sse[d] = v;
}

// ---------- scoring GCN (F=1), unweighted masked adjacency ----------
__global__ void k_score(const int* __restrict__ rowptr, const int* __restrict__ csr_src,
                        const int* __restrict__ alive, const float* __restrict__ dinvU,
                        const float* __restrict__ sse, const float* __restrict__ bp,
                        float* __restrict__ score) {
  int d = blockIdx.x*256 + threadIdx.x;
  if (d >= BNODES) return;
  float du = dinvU[d];
  float acc = du*du*sse[d] + bp[0];
  if (alive[d]) {
    int r1 = rowptr[d+1];
    for (int j = rowptr[d]; j < r1; ++j) {
      int s = csr_src[j];
      if (alive[s]) acc += du * dinvU[s] * sse[s];
    }
  }
  score[d] = acc;
}

// ---------- top-k (exact jax.lax.top_k tie semantics) + pool-scale + readout ----------
__global__ void k_topk_readout(const float* __restrict__ score, const int* __restrict__ alive,
                               int k, float kf, float* __restrict__ h,
                               int* __restrict__ aliveNext, float* __restrict__ g) {
  __shared__ float s[NN];
  __shared__ float tm[NN];
  __shared__ float smx[16][FH];
  __shared__ float ssm[16][FH];
  int b = blockIdx.x, t = threadIdx.x;
  int node = b*NN + t;
  float raw = score[node];
  float masked = alive[node] ? raw : -INFINITY;
  s[t] = masked;
  __syncthreads();
  int rank = 0;
  for (int j = 0; j < NN; ++j) {
    float o = s[j];
    rank += (o > masked) || (o == masked && j < t);
  }
  int sel = (rank < k) ? 1 : 0;
  aliveNext[node] = sel;
  __syncthreads();
  tm[t] = sel ? tanhf(raw) : 0.f;
  s[t] = sel ? 1.f : 0.f;
  __syncthreads();
  int f = t & 63, r = t >> 6;          // wave r handles nodes r, r+16, ...
  float mx = -INFINITY, sm = 0.f;
  float* hb = h + (size_t)b*NN*FH;
  for (int kk = 0; kk < 64; ++kk) {
    int n = r + kk*16;
    float tv = tm[n];
    size_t idx = (size_t)n*FH + f;
    float v = hb[idx] * tv;
    hb[idx] = v;
    if (s[n] != 0.f) { mx = fmaxf(mx, v); sm += v; }
  }
  smx[r][f] = mx; ssm[r][f] = sm;
  __syncthreads();
  if (t < FH) {
    float m2 = -INFINITY, s2 = 0.f;
    #pragma unroll
    for (int rr = 0; rr < 16; ++rr) { m2 = fmaxf(m2, smx[rr][t]); s2 += ssm[rr][t]; }
    g[b*2*FH + t] += m2;
    g[b*2*FH + FH + t] += s2 / kf;
  }
}

// ---------- MLP head + log_softmax ----------
__global__ void k_mlp(const float* __restrict__ g,
                      const float* __restrict__ Wl1, const float* __restrict__ bl1,
                      const float* __restrict__ Wl2, const float* __restrict__ bl2,
                      const float* __restrict__ Wl3, const float* __restrict__ bl3,
                      float* __restrict__ out) {
  __shared__ float sg[2*FH];
  __shared__ float l1[FH];
  __shared__ float l2[FH/2];
  __shared__ float l3[2];
  int b = blockIdx.x, t = threadIdx.x;
  sg[t] = g[b*2*FH + t];
  sg[FH + t] = g[b*2*FH + FH + t];
  __syncthreads();
  float acc = bl1[t];
  #pragma unroll
  for (int k = 0; k < 2*FH; ++k) acc = fmaf(sg[k], Wl1[k*FH + t], acc);
  l1[t] = fmaxf(acc, 0.f);
  __syncthreads();
  if (t < 32) {
    float a2 = bl2[t];
    #pragma unroll
    for (int k = 0; k < FH; ++k) a2 = fmaf(l1[k], Wl2[k*32 + t], a2);
    l2[t] = fmaxf(a2, 0.f);
  }
  __syncthreads();
  if (t < 2) {
    float a3 = bl3[t];
    #pragma unroll
    for (int k = 0; k < 32; ++k) a3 = fmaf(l2[k], Wl3[k*2 + t], a3);
    l3[t] = a3;
  }
  __syncthreads();
  if (t == 0) {
    float m = fmaxf(l3[0], l3[1]);
    float lse = m + logf(expf(l3[0]-m) + expf(l3[1]-m));
    out[b*2+0] = l3[0] - lse;
    out[b*2+1] = l3[1] - lse;
  }
}

extern "C" void kernel_launch(void* const* d_in, const int* in_sizes, int n_in,
                              void* d_out, int out_size, void* d_ws, size_t ws_size,
                              hipStream_t stream) {
  const float* x   = (const float*)d_in[0];
  const float* ea  = (const float*)d_in[1];
  const float* W1  = (const float*)d_in[2];
  const float* b1  = (const float*)d_in[3];
  const float* Wp1 = (const float*)d_in[4];
  const float* bp1 = (const float*)d_in[5];
  const float* W2  = (const float*)d_in[6];
  const float* b2  = (const float*)d_in[7];
  const float* Wp2 = (const float*)d_in[8];
  const float* bp2 = (const float*)d_in[9];
  const float* W3  = (const float*)d_in[10];
  const float* b3  = (const float*)d_in[11];
  const float* Wp3 = (const float*)d_in[12];
  const float* bp3 = (const float*)d_in[13];
  const float* Wl1 = (const float*)d_in[14];
  const float* bl1 = (const float*)d_in[15];
  const float* Wl2 = (const float*)d_in[16];
  const float* bl2 = (const float*)d_in[17];
  const float* Wl3 = (const float*)d_in[18];
  const float* bl3 = (const float*)d_in[19];
  const int*   ei  = (const int*)d_in[20];
  float* out = (float*)d_out;

  float* hA    = (float*)d_ws;                       // BNODES*FH
  float* hB    = hA + (size_t)BNODES*FH;             // BNODES*FH
  float* dinvW = hB + (size_t)BNODES*FH;             // BNODES
  float* dinvU = dinvW + BNODES;                     // BNODES
  float* sse   = dinvU + BNODES;                     // BNODES
  float* score = sse + BNODES;                       // BNODES
  float* g     = score + BNODES;                     // NB*2*FH
  int* aliveA  = (int*)(g + NB*2*FH);                // BNODES
  int* aliveB  = aliveA + BNODES;                    // BNODES
  int* cnt     = aliveB + BNODES;                    // BNODES
  int* rowptr  = cnt + BNODES;                       // BNODES+1
  int* cursor  = rowptr + BNODES + 1;                // BNODES
  int* csr_src = cursor + BNODES;                    // NE
  float* csr_w = (float*)(csr_src + NE);             // NE

  const int TB = 256;
  const int gE  = NE / TB;
  const int gN  = BNODES / TB;
  const int gNH = BNODES*FH / TB;
  const int gW  = BNODES*64 / TB;   // one wave per node

  // CSR build (reused by all 6 aggregation passes)
  k_init<<<gN, TB, 0, stream>>>(cnt, aliveA, g);
  k_count<<<gE, TB, 0, stream>>>(ei, cnt);
  k_scan<<<1, 1024, 0, stream>>>(cnt, rowptr, cursor);
  k_fill<<<gE, TB, 0, stream>>>(ei, ea, cursor, csr_src, csr_w);

  // ===== Layer 1 (w = edge_attr, all alive) =====
  k_degs<0><<<gN, TB, 0, stream>>>(rowptr, csr_src, csr_w, aliveA, dinvW, dinvU);
  k_lin1<<<gNH, TB, 0, stream>>>(x, W1, hB);
  k_gather<0><<<gW, TB, 0, stream>>>(rowptr, csr_src, csr_w, aliveA, dinvW, hB, b1, Wp1, hA, sse);
  k_score<<<gN, TB, 0, stream>>>(rowptr, csr_src, aliveA, dinvU, sse, bp1, score);
  k_topk_readout<<<NB, NN, 0, stream>>>(score, aliveA, KK1, (float)KK1, hA, aliveB, g);

  // ===== Layer 2 (w = edge_attr * mask(a1)) =====
  k_degs<1><<<gN, TB, 0, stream>>>(rowptr, csr_src, csr_w, aliveB, dinvW, dinvU);
  k_lin64<<<4096, TB, 0, stream>>>(hA, W2, hB);
  k_gather<1><<<gW, TB, 0, stream>>>(rowptr, csr_src, csr_w, aliveB, dinvW, hB, b2, Wp2, hA, sse);
  k_score<<<gN, TB, 0, stream>>>(rowptr, csr_src, aliveB, dinvU, sse, bp2, score);
  k_topk_readout<<<NB, NN, 0, stream>>>(score, aliveB, KK2, (float)KK2, hA, aliveA, g);

  // ===== Layer 3 (w = mask(a2), conv3 unweighted) =====
  k_degs<2><<<gN, TB, 0, stream>>>(rowptr, csr_src, csr_w, aliveA, dinvW, dinvU);
  k_lin64<<<4096, TB, 0, stream>>>(hA, W3, hB);
  k_gather<2><<<gW, TB, 0, stream>>>(rowptr, csr_src, csr_w, aliveA, dinvW, hB, b3, Wp3, hA, sse);
  k_score<<<gN, TB, 0, stream>>>(rowptr, csr_src, aliveA, dinvU, sse, bp3, score);
  k_topk_readout<<<NB, NN, 0, stream>>>(score, aliveA, KK3, (float)KK3, hA, aliveB, g);

  k_mlp<<<NB, FH, 0, stream>>>(g, Wl1, bl1, Wl2, bl2, Wl3, bl3, out);
}